// Round 4
// baseline (319.132 us; speedup 1.0000x reference)
//
#include <hip/hip_runtime.h>

#define BATCHN 32768

typedef _Float16 h8  __attribute__((ext_vector_type(8)));
typedef _Float16 h4  __attribute__((ext_vector_type(4)));
typedef _Float16 h2v __attribute__((ext_vector_type(2)));
typedef __fp16   fp16x2 __attribute__((ext_vector_type(2)));
typedef float    f4  __attribute__((ext_vector_type(4)));

// ---- ws layout (f16 elements) ----
// WQ1 [2][128][32] @0      (blk0: qw1 rows 0..31 state; blk1: rows 33..64 mi)
// WQ2 [4][128][32] @8192
// WM1 [1][128][32] @24576  (mw1 rows 1..32)
// WM2 [4][128][32] @28672
// WM3 [4][64][32]  @45056
#define WM1E 24576
#define WM2E 28672
#define WM3E 45056

// ---- LDS layout (bytes); all rows are 64B (32 f16), XOR-swizzled ----
#define ABUF 0        // 4 k-blocks x [128][32] f16 = 32768
#define MSG  32768    // 4 depths x 2 cidx x [128][32] f16 = 65536
#define LDS_TOTAL 98304

#define MFMA16(a,b,c) __builtin_amdgcn_mfma_f32_16x16x32_f16(a,b,c,0,0,0)

__device__ __forceinline__ float tanh_fast(float v){
  float e = __expf(2.0f*v);
  return 1.0f - 2.0f/(e+1.0f);
}
__device__ __forceinline__ h2v cvt2(float a, float b){
  fp16x2 t = __builtin_amdgcn_cvt_pkrtz(a, b);
  union { fp16x2 i; h2v o; } u; u.i = t; return u.o;
}
__device__ __forceinline__ h4 relu4h(f4 v){
  union { h4 v4; h2v p[2]; } u;
  u.p[0] = cvt2(fmaxf(v[0],0.f), fmaxf(v[1],0.f));
  u.p[1] = cvt2(fmaxf(v[2],0.f), fmaxf(v[3],0.f));
  return u.v4;
}
__device__ __forceinline__ h8 pack8(f4 a, f4 b){
  union { h8 v8; h2v p[4]; } u;
  u.p[0] = cvt2(a[0],a[1]); u.p[1] = cvt2(a[2],a[3]);
  u.p[2] = cvt2(b[0],b[1]); u.p[3] = cvt2(b[2],b[3]);
  return u.v8;
}
__device__ __forceinline__ h8 tanh8(h8 s){
  h8 r;
  #pragma unroll
  for (int j=0;j<8;++j) r[j] = (_Float16)tanh_fast((float)s[j]);
  return r;
}

// ---------------- weight prep: fp32 -> f16 blocked layouts ----------------
__global__ void critic_prep(const float* __restrict__ qw1, const float* __restrict__ qw2,
                            const float* __restrict__ mw1, const float* __restrict__ mw2,
                            const float* __restrict__ mw3, _Float16* __restrict__ ws)
{
  int i = blockIdx.x*blockDim.x + threadIdx.x;
  if (i < 8192){ int ks=i>>12, r=i&4095, f=r>>5, kk=r&31;
    ws[i] = (_Float16)(ks==0 ? qw1[kk*128+f] : qw1[(33+kk)*128+f]); return; }
  i -= 8192;
  if (i < 16384){ int ks=i>>12, r=i&4095, f=r>>5, kk=r&31;
    ws[8192+i] = (_Float16)qw2[(ks*32+kk)*128+f]; return; }
  i -= 16384;
  if (i < 4096){ int f=i>>5, kk=i&31;
    ws[WM1E+i] = (_Float16)mw1[(1+kk)*128+f]; return; }
  i -= 4096;
  if (i < 16384){ int ks=i>>12, r=i&4095, f=r>>5, kk=r&31;
    ws[WM2E+i] = (_Float16)mw2[(ks*32+kk)*128+f]; return; }
  i -= 16384;
  if (i < 8192){ int ks=i>>11, r=i&2047, f=r>>5, kk=r&31;
    ws[WM3E+i] = (_Float16)mw3[(ks*32+kk)*64+f]; return; }
}

// ---------------- single fused kernel: all 20 limbs, DFS, zero barriers ----------------
__global__ __launch_bounds__(256,1) void critic_all(
    const float* __restrict__ state, const float* __restrict__ action,
    const float* __restrict__ qw1, const float* __restrict__ qb1,
    const float* __restrict__ qb2, const float* __restrict__ qw3,
    const float* __restrict__ qb3, const float* __restrict__ mw1,
    const float* __restrict__ mb1, const float* __restrict__ mb2,
    const float* __restrict__ mb3,
    const _Float16* __restrict__ ws, float* __restrict__ out)
{
  extern __shared__ char sm[];
  const int tid = threadIdx.x, lane = tid & 63;
  const int w = tid >> 6, g = lane >> 4, li = lane & 15;
  const int rbase = blockIdx.x*128 + w*32;

  // persistent q1/q2 A-fragments (192 VGPRs), loaded once from global
  h8 aq1[2][8], aq2[4][8];
  #pragma unroll
  for (int ks=0; ks<2; ++ks)
    #pragma unroll
    for (int t=0; t<8; ++t)
      aq1[ks][t] = *(const h8*)(ws + ks*4096 + (16*t+li)*32 + 8*g);
  #pragma unroll
  for (int ks=0; ks<4; ++ks)
    #pragma unroll
    for (int t=0; t<8; ++t)
      aq2[ks][t] = *(const h8*)(ws + 8192 + ks*4096 + (16*t+li)*32 + 8*g);

  // wave-private LDS rows + precomputed swizzle (loop-invariant)
  const int row0 = w*32 + li, row1 = w*32 + 16 + li;
  const int sw0 = ((row0>>1)&3)<<4, sw1 = ((row1>>1)&3)<<4;
  const int rb0 = row0*64, rb1 = row1*64;

  const h8 hzero = {};
  float xsum0 = 0.f, xsum1 = 0.f;

  const float* srow0 = state + (size_t)(rbase+li)*640 + 8*g;
  const float* srow1 = state + (size_t)(rbase+16+li)*640 + 8*g;

  // DFS order + depths (5/3 bits per entry)
  const unsigned long long SEQ0 =
    (0ull)|(1ull<<5)|(3ull<<10)|(7ull<<15)|(15ull<<20)|(16ull<<25)|(8ull<<30)|
    (17ull<<35)|(18ull<<40)|(4ull<<45)|(9ull<<50)|(19ull<<55);
  const unsigned long long SEQ1 =
    (10ull)|(2ull<<5)|(5ull<<10)|(11ull<<15)|(12ull<<20)|(6ull<<25)|(13ull<<30)|(14ull<<35);
  const unsigned long long DEPS =
    (0ull)|(1ull<<3)|(2ull<<6)|(3ull<<9)|(4ull<<12)|(4ull<<15)|(3ull<<18)|(4ull<<21)|
    (4ull<<24)|(2ull<<27)|(3ull<<30)|(4ull<<33)|(3ull<<36)|(1ull<<39)|(2ull<<42)|
    (3ull<<45)|(3ull<<48)|(2ull<<51)|(3ull<<54)|(3ull<<57);

  // prefetch limb 0 (limb id 0)
  f4 va0 = *(const f4*)(srow0),   vb0 = *(const f4*)(srow0+4);
  f4 va1 = *(const f4*)(srow1),   vb1 = *(const f4*)(srow1+4);
  float act0 = action[rbase+li], act1 = action[rbase+16+li];

  #pragma unroll 1
  for (int i = 0; i < 20; ++i){
    const int limb  = (int)(((i<12) ? (SEQ0>>(5*i)) : (SEQ1>>(5*(i-12)))) & 31);
    const int depth = (int)((DEPS >> (3*i)) & 7);
    const int cidx  = (limb-1) & 1;

    // capture current inputs, then issue next-limb prefetch (hides L3 latency)
    h8 bf00 = pack8(va0, vb0), bf01 = pack8(va1, vb1);
    const float a0 = act0, a1 = act1;
    if (i < 19){
      const int nl = (int)(((i+1<12) ? (SEQ0>>(5*(i+1))) : (SEQ1>>(5*(i-11)))) & 31);
      va0 = *(const f4*)(srow0 + nl*32); vb0 = *(const f4*)(srow0 + nl*32 + 4);
      va1 = *(const f4*)(srow1 + nl*32); vb1 = *(const f4*)(srow1 + nl*32 + 4);
      act0 = action[(size_t)nl*BATCHN + rbase + li];
      act1 = action[(size_t)nl*BATCHN + rbase + 16 + li];
    }

    // mi fragments from parent msg slot (wave-private, swizzled)
    h8 bf1[2];
    if (limb > 0){
      const char* mr = sm + MSG + (depth-1)*16384 + cidx*8192;
      bf1[0] = *(const h8*)(mr + rb0 + (16*g ^ sw0));
      bf1[1] = *(const h8*)(mr + rb1 + (16*g ^ sw1));
    } else { bf1[0] = hzero; bf1[1] = hzero; }

    // ---- q1: acc = qb1 + act*wa (rank-1) + state@W + mi@W ----
    f4 acc[8][2];
    #pragma unroll
    for (int t=0; t<8; ++t){
      f4 bv = *(const f4*)(qb1 + 16*t + 4*g);
      f4 wa = *(const f4*)(qw1 + 4096 + 16*t + 4*g);   // row 32 = action weights
      acc[t][0] = bv + a0*wa;
      acc[t][1] = bv + a1*wa;
    }
    #pragma unroll
    for (int t=0; t<8; ++t){
      acc[t][0] = MFMA16(aq1[0][t], bf00, acc[t][0]);
      acc[t][1] = MFMA16(aq1[0][t], bf01, acc[t][1]);
      acc[t][0] = MFMA16(aq1[1][t], bf1[0], acc[t][0]);
      acc[t][1] = MFMA16(aq1[1][t], bf1[1], acc[t][1]);
    }
    // handoff h1 -> ABUF (relu, f16, swizzled)
    #pragma unroll
    for (int t=0; t<8; ++t){
      const int c = (t&1)*32 + 8*g;
      *(h4*)(sm + ABUF + (t>>1)*8192 + rb0 + (c ^ sw0)) = relu4h(acc[t][0]);
      *(h4*)(sm + ABUF + (t>>1)*8192 + rb1 + (c ^ sw1)) = relu4h(acc[t][1]);
    }

    // ---- q2 ----
    #pragma unroll
    for (int t=0; t<8; ++t){
      f4 bv = *(const f4*)(qb2 + 16*t + 4*g);
      acc[t][0] = bv; acc[t][1] = bv;
    }
    #pragma unroll
    for (int ks=0; ks<4; ++ks){
      h8 b0 = *(const h8*)(sm + ABUF + ks*8192 + rb0 + (16*g ^ sw0));
      h8 b1 = *(const h8*)(sm + ABUF + ks*8192 + rb1 + (16*g ^ sw1));
      #pragma unroll
      for (int t=0; t<8; ++t){
        acc[t][0] = MFMA16(aq2[ks][t], b0, acc[t][0]);
        acc[t][1] = MFMA16(aq2[ks][t], b1, acc[t][1]);
      }
    }
    // ---- x = relu(h2).w3 + b3 ----
    float xs0 = 0.f, xs1 = 0.f;
    #pragma unroll
    for (int t=0; t<8; ++t){
      f4 wv = *(const f4*)(qw3 + 16*t + 4*g);
      #pragma unroll
      for (int r=0; r<4; ++r){
        xs0 += fmaxf(acc[t][0][r],0.f)*wv[r];
        xs1 += fmaxf(acc[t][1][r],0.f)*wv[r];
      }
    }
    xs0 += __shfl_xor(xs0,16,64); xs0 += __shfl_xor(xs0,32,64);
    xs1 += __shfl_xor(xs1,16,64); xs1 += __shfl_xor(xs1,32,64);
    const float b3 = qb3[0];
    xs0 += b3; xs1 += b3;
    xsum0 += xs0; xsum1 += xs1;

    // ---- message net (writers: limbs 0..9) ----
    if (limb < 10){
      const float tx0 = tanh_fast(xs0), tx1 = tanh_fast(xs1);
      h8 tf0 = tanh8(bf1[0]), tf1 = tanh8(bf1[1]);
      // m1: init = mb1 + tx*wx (rank-1, wx = mw1 row 0); one MFMA block for mi
      #pragma unroll
      for (int t=0; t<8; ++t){
        f4 bm = *(const f4*)(mb1 + 16*t + 4*g);
        f4 wx = *(const f4*)(mw1 + 16*t + 4*g);
        acc[t][0] = bm + tx0*wx;
        acc[t][1] = bm + tx1*wx;
      }
      #pragma unroll
      for (int t=0; t<8; ++t){
        h8 a = *(const h8*)(ws + WM1E + (16*t+li)*32 + 8*g);
        acc[t][0] = MFMA16(a, tf0, acc[t][0]);
        acc[t][1] = MFMA16(a, tf1, acc[t][1]);
      }
      #pragma unroll
      for (int t=0; t<8; ++t){
        const int c = (t&1)*32 + 8*g;
        *(h4*)(sm + ABUF + (t>>1)*8192 + rb0 + (c ^ sw0)) = relu4h(acc[t][0]);
        *(h4*)(sm + ABUF + (t>>1)*8192 + rb1 + (c ^ sw1)) = relu4h(acc[t][1]);
      }
      // m2: A-frags from global (L2-hot), bias via VALU init
      #pragma unroll
      for (int t=0; t<8; ++t){
        f4 bv = *(const f4*)(mb2 + 16*t + 4*g);
        acc[t][0] = bv; acc[t][1] = bv;
      }
      #pragma unroll
      for (int ks=0; ks<4; ++ks){
        h8 b0 = *(const h8*)(sm + ABUF + ks*8192 + rb0 + (16*g ^ sw0));
        h8 b1 = *(const h8*)(sm + ABUF + ks*8192 + rb1 + (16*g ^ sw1));
        #pragma unroll
        for (int t=0; t<8; ++t){
          h8 a = *(const h8*)(ws + WM2E + ks*4096 + (16*t+li)*32 + 8*g);
          acc[t][0] = MFMA16(a, b0, acc[t][0]);
          acc[t][1] = MFMA16(a, b1, acc[t][1]);
        }
      }
      #pragma unroll
      for (int t=0; t<8; ++t){
        const int c = (t&1)*32 + 8*g;
        *(h4*)(sm + ABUF + (t>>1)*8192 + rb0 + (c ^ sw0)) = relu4h(acc[t][0]);
        *(h4*)(sm + ABUF + (t>>1)*8192 + rb1 + (c ^ sw1)) = relu4h(acc[t][1]);
      }
      // m3: 64 feats, A-frags global, bias via VALU init
      f4 accN[4][2];
      #pragma unroll
      for (int t=0; t<4; ++t){
        f4 bv = *(const f4*)(mb3 + 16*t + 4*g);
        accN[t][0] = bv; accN[t][1] = bv;
      }
      #pragma unroll
      for (int ks=0; ks<4; ++ks){
        h8 b0 = *(const h8*)(sm + ABUF + ks*8192 + rb0 + (16*g ^ sw0));
        h8 b1 = *(const h8*)(sm + ABUF + ks*8192 + rb1 + (16*g ^ sw1));
        #pragma unroll
        for (int t=0; t<4; ++t){
          h8 a = *(const h8*)(ws + WM3E + ks*2048 + (16*t+li)*32 + 8*g);
          accN[t][0] = MFMA16(a, b0, accN[t][0]);
          accN[t][1] = MFMA16(a, b1, accN[t][1]);
        }
      }
      // l2 norm + store md to this depth's msg slot (swizzled)
      float s0=0.f, s1=0.f;
      #pragma unroll
      for (int t=0; t<4; ++t)
        #pragma unroll
        for (int r=0; r<4; ++r){
          s0 += accN[t][0][r]*accN[t][0][r];
          s1 += accN[t][1][r]*accN[t][1][r];
        }
      s0 += __shfl_xor(s0,16,64); s0 += __shfl_xor(s0,32,64);
      s1 += __shfl_xor(s1,16,64); s1 += __shfl_xor(s1,32,64);
      const float inv0 = 1.0f/fmaxf(sqrtf(s0),1e-12f);
      const float inv1 = 1.0f/fmaxf(sqrtf(s1),1e-12f);
      char* md = sm + MSG + depth*16384;
      #pragma unroll
      for (int t=0; t<4; ++t){
        const int c = (t&1)*32 + 8*g;
        f4 v0 = accN[t][0], v1 = accN[t][1];
        union { h4 v4; h2v p[2]; } u0, u1;
        u0.p[0] = cvt2(v0[0]*inv0, v0[1]*inv0);
        u0.p[1] = cvt2(v0[2]*inv0, v0[3]*inv0);
        u1.p[0] = cvt2(v1[0]*inv1, v1[1]*inv1);
        u1.p[1] = cvt2(v1[2]*inv1, v1[3]*inv1);
        *(h4*)(md + (t>>1)*8192 + rb0 + (c ^ sw0)) = u0.v4;
        *(h4*)(md + (t>>1)*8192 + rb1 + (c ^ sw1)) = u1.v4;
      }
    }
  }
  if (g == 0){
    out[rbase + li]      = xsum0;
    out[rbase + 16 + li] = xsum1;
  }
}

extern "C" void kernel_launch(void* const* d_in, const int* in_sizes, int n_in,
                              void* d_out, int out_size, void* d_ws, size_t ws_size,
                              hipStream_t stream) {
  (void)in_sizes; (void)n_in; (void)out_size; (void)ws_size;
  const float* state  = (const float*)d_in[0];
  const float* action = (const float*)d_in[1];
  const float* qw1 = (const float*)d_in[2];
  const float* qb1 = (const float*)d_in[3];
  const float* qw2 = (const float*)d_in[4];
  const float* qb2 = (const float*)d_in[5];
  const float* qw3 = (const float*)d_in[6];
  const float* qb3 = (const float*)d_in[7];
  const float* mw1 = (const float*)d_in[8];
  const float* mb1 = (const float*)d_in[9];
  const float* mw2 = (const float*)d_in[10];
  const float* mb2 = (const float*)d_in[11];
  const float* mw3 = (const float*)d_in[12];
  const float* mb3 = (const float*)d_in[13];
  _Float16* ws = (_Float16*)d_ws;
  float* out = (float*)d_out;

  (void)hipFuncSetAttribute((const void*)critic_all,
                            hipFuncAttributeMaxDynamicSharedMemorySize, LDS_TOTAL);

  critic_prep<<<208, 256, 0, stream>>>(qw1, qw2, mw1, mw2, mw3, ws);
  critic_all<<<256, 256, LDS_TOTAL, stream>>>(
      state, action, qw1, qb1, qb2, qw3, qb3, mw1, mb1, mb2, mb3, ws, out);
}

// Round 5
// 164.338 us; speedup vs baseline: 1.9419x; 1.9419x over previous
//
#include <hip/hip_runtime.h>

#define BATCHN 32768

typedef _Float16 h8  __attribute__((ext_vector_type(8)));
typedef _Float16 h4  __attribute__((ext_vector_type(4)));
typedef _Float16 h2v __attribute__((ext_vector_type(2)));
typedef __fp16   fp16x2 __attribute__((ext_vector_type(2)));
typedef float    f4  __attribute__((ext_vector_type(4)));
typedef unsigned int u32x4 __attribute__((ext_vector_type(4)));

// ---- ws layout (f16 elements) ----
// WQ1 [2][128][32] @0      linear (register loads)
// WQ2 [4][128][32] @8192   linear (register loads)
// WM1 [1][128][32] @24576  col-swizzled (copied to LDS)
// WM2 [4][128][32] @28672  col-swizzled (copied to LDS)
// WM3 [4][64][32]  @45056  linear (global A-frags)
#define WM1E 24576
#define WM2E 28672
#define WM3E 45056

// ---- LDS layout (bytes); rows are 64B (32 f16), XOR-swizzled ----
#define LM1  0        // [128][32] f16 = 8192
#define LM2  8192     // 4 x [128][32] f16 = 32768
#define ABUF 40960    // 4 k-blocks x [128][32] f16 = 32768
#define MSG  73728    // 4 depths x 2 cidx x [128][32] f16 = 65536
#define LDS_TOTAL 139264

#define MFMA16(a,b,c) __builtin_amdgcn_mfma_f32_16x16x32_f16(a,b,c,0,0,0)

__device__ __forceinline__ float tanh_fast(float v){
  float e = __expf(2.0f*v);
  return 1.0f - 2.0f/(e+1.0f);
}
__device__ __forceinline__ h2v cvt2(float a, float b){
  fp16x2 t = __builtin_amdgcn_cvt_pkrtz(a, b);
  union { fp16x2 i; h2v o; } u; u.i = t; return u.o;
}
__device__ __forceinline__ h4 relu4h(f4 v){
  union { h4 v4; h2v p[2]; } u;
  u.p[0] = cvt2(fmaxf(v[0],0.f), fmaxf(v[1],0.f));
  u.p[1] = cvt2(fmaxf(v[2],0.f), fmaxf(v[3],0.f));
  return u.v4;
}
__device__ __forceinline__ h8 pack8(f4 a, f4 b){
  union { h8 v8; h2v p[4]; } u;
  u.p[0] = cvt2(a[0],a[1]); u.p[1] = cvt2(a[2],a[3]);
  u.p[2] = cvt2(b[0],b[1]); u.p[3] = cvt2(b[2],b[3]);
  return u.v8;
}
__device__ __forceinline__ h8 tanh8(h8 s){
  h8 r;
  #pragma unroll
  for (int j=0;j<8;++j) r[j] = (_Float16)tanh_fast((float)s[j]);
  return r;
}

// ---------------- weight prep: fp32 -> f16 blocked layouts ----------------
__global__ void critic_prep(const float* __restrict__ qw1, const float* __restrict__ qw2,
                            const float* __restrict__ mw1, const float* __restrict__ mw2,
                            const float* __restrict__ mw3, _Float16* __restrict__ ws)
{
  int i = blockIdx.x*blockDim.x + threadIdx.x;
  if (i < 8192){ int ks=i>>12, r=i&4095, f=r>>5, kk=r&31;
    ws[i] = (_Float16)(ks==0 ? qw1[kk*128+f] : qw1[(33+kk)*128+f]); return; }
  i -= 8192;
  if (i < 16384){ int ks=i>>12, r=i&4095, f=r>>5, kk=r&31;
    ws[8192+i] = (_Float16)qw2[(ks*32+kk)*128+f]; return; }
  i -= 16384;
  if (i < 4096){ int f=i>>5, kks=i&31;              // col-swizzled
    int kk = kks ^ (((f>>1)&3)<<3);
    ws[WM1E+i] = (_Float16)mw1[(1+kk)*128+f]; return; }
  i -= 4096;
  if (i < 16384){ int ks=i>>12, r=i&4095, f=r>>5, kks=r&31;   // col-swizzled
    int kk = kks ^ (((f>>1)&3)<<3);
    ws[WM2E+i] = (_Float16)mw2[(ks*32+kk)*128+f]; return; }
  i -= 16384;
  if (i < 8192){ int ks=i>>11, r=i&2047, f=r>>5, kk=r&31;     // linear
    ws[WM3E+i] = (_Float16)mw3[(ks*32+kk)*64+f]; return; }
}

// ---------------- single fused kernel: all 20 limbs, DFS, one barrier ----------------
__global__ __launch_bounds__(256,1) void critic_all(
    const float* __restrict__ state, const float* __restrict__ action,
    const float* __restrict__ qw1, const float* __restrict__ qb1,
    const float* __restrict__ qb2, const float* __restrict__ qw3,
    const float* __restrict__ qb3, const float* __restrict__ mw1,
    const float* __restrict__ mb1, const float* __restrict__ mb2,
    const float* __restrict__ mb3,
    const _Float16* __restrict__ ws, float* __restrict__ out)
{
  extern __shared__ char sm[];
  const int tid = threadIdx.x, lane = tid & 63;
  const int w = tid >> 6, g = lane >> 4, li = lane & 15;
  const int rbase = blockIdx.x*128 + w*32;

  // copy col-swizzled m1,m2 weights into LDS (40KB, ws bytes 49152..90111)
  for (int off = tid*16; off < 40960; off += 4096)
    *(u32x4*)(sm + off) = *(const u32x4*)((const char*)ws + 49152 + off);

  // persistent q1/q2 A-fragments (192 VGPRs), loaded once from global
  h8 aq1[2][8], aq2[4][8];
  #pragma unroll
  for (int ks=0; ks<2; ++ks)
    #pragma unroll
    for (int t=0; t<8; ++t)
      aq1[ks][t] = *(const h8*)(ws + ks*4096 + (16*t+li)*32 + 8*g);
  #pragma unroll
  for (int ks=0; ks<4; ++ks)
    #pragma unroll
    for (int t=0; t<8; ++t)
      aq2[ks][t] = *(const h8*)(ws + 8192 + ks*4096 + (16*t+li)*32 + 8*g);

  __syncthreads();   // the only barrier

  // wave-private LDS rows + loop-invariant swizzles
  const int row0 = w*32 + li, row1 = w*32 + 16 + li;
  const int sw0 = ((row0>>1)&3)<<4, sw1 = ((row1>>1)&3)<<4;
  const int swA = ((li>>1)&3)<<4;          // weight-row swizzle (row=16t+li)
  const int rb0 = row0*64, rb1 = row1*64;

  const h8 hzero = {};
  float xsum0 = 0.f, xsum1 = 0.f;

  const float* srow0 = state + (size_t)(rbase+li)*640 + 8*g;
  const float* srow1 = state + (size_t)(rbase+16+li)*640 + 8*g;

  // DFS order + depths (5/3 bits per entry)
  const unsigned long long SEQ0 =
    (0ull)|(1ull<<5)|(3ull<<10)|(7ull<<15)|(15ull<<20)|(16ull<<25)|(8ull<<30)|
    (17ull<<35)|(18ull<<40)|(4ull<<45)|(9ull<<50)|(19ull<<55);
  const unsigned long long SEQ1 =
    (10ull)|(2ull<<5)|(5ull<<10)|(11ull<<15)|(12ull<<20)|(6ull<<25)|(13ull<<30)|(14ull<<35);
  const unsigned long long DEPS =
    (0ull)|(1ull<<3)|(2ull<<6)|(3ull<<9)|(4ull<<12)|(4ull<<15)|(3ull<<18)|(4ull<<21)|
    (4ull<<24)|(2ull<<27)|(3ull<<30)|(4ull<<33)|(3ull<<36)|(1ull<<39)|(2ull<<42)|
    (3ull<<45)|(3ull<<48)|(2ull<<51)|(3ull<<54)|(3ull<<57);

  // prefetch limb 0
  f4 va0 = *(const f4*)(srow0),   vb0 = *(const f4*)(srow0+4);
  f4 va1 = *(const f4*)(srow1),   vb1 = *(const f4*)(srow1+4);
  float act0 = action[rbase+li], act1 = action[rbase+16+li];

  #pragma unroll 1
  for (int i = 0; i < 20; ++i){
    const int limb  = (int)(((i<12) ? (SEQ0>>(5*i)) : (SEQ1>>(5*(i-12)))) & 31);
    const int depth = (int)((DEPS >> (3*i)) & 7);
    const int cidx  = (limb-1) & 1;

    // capture current inputs, then issue next-limb prefetch
    h8 bf00 = pack8(va0, vb0), bf01 = pack8(va1, vb1);
    const float a0 = act0, a1 = act1;
    if (i < 19){
      const int nl = (int)(((i+1<12) ? (SEQ0>>(5*(i+1))) : (SEQ1>>(5*(i-11)))) & 31);
      va0 = *(const f4*)(srow0 + nl*32); vb0 = *(const f4*)(srow0 + nl*32 + 4);
      va1 = *(const f4*)(srow1 + nl*32); vb1 = *(const f4*)(srow1 + nl*32 + 4);
      act0 = action[(size_t)nl*BATCHN + rbase + li];
      act1 = action[(size_t)nl*BATCHN + rbase + 16 + li];
    }

    // mi fragments from parent msg slot (wave-private, swizzled)
    h8 bf1[2];
    if (limb > 0){
      const char* mr = sm + MSG + (depth-1)*16384 + cidx*8192;
      bf1[0] = *(const h8*)(mr + rb0 + (16*g ^ sw0));
      bf1[1] = *(const h8*)(mr + rb1 + (16*g ^ sw1));
    } else { bf1[0] = hzero; bf1[1] = hzero; }

    // ---- q1: acc = qb1 + act*wa (rank-1) + state@W + mi@W ----
    f4 acc[8][2];
    #pragma unroll
    for (int t=0; t<8; ++t){
      f4 bv = *(const f4*)(qb1 + 16*t + 4*g);
      f4 wa = *(const f4*)(qw1 + 4096 + 16*t + 4*g);   // row 32 = action weights
      acc[t][0] = bv + a0*wa;
      acc[t][1] = bv + a1*wa;
    }
    #pragma unroll
    for (int t=0; t<8; ++t){
      acc[t][0] = MFMA16(aq1[0][t], bf00, acc[t][0]);
      acc[t][1] = MFMA16(aq1[0][t], bf01, acc[t][1]);
      acc[t][0] = MFMA16(aq1[1][t], bf1[0], acc[t][0]);
      acc[t][1] = MFMA16(aq1[1][t], bf1[1], acc[t][1]);
    }
    // handoff h1 -> ABUF (relu, f16, swizzled)
    #pragma unroll
    for (int t=0; t<8; ++t){
      const int c = (t&1)*32 + 8*g;
      *(h4*)(sm + ABUF + (t>>1)*8192 + rb0 + (c ^ sw0)) = relu4h(acc[t][0]);
      *(h4*)(sm + ABUF + (t>>1)*8192 + rb1 + (c ^ sw1)) = relu4h(acc[t][1]);
    }

    // ---- q2 ----
    #pragma unroll
    for (int t=0; t<8; ++t){
      f4 bv = *(const f4*)(qb2 + 16*t + 4*g);
      acc[t][0] = bv; acc[t][1] = bv;
    }
    #pragma unroll
    for (int ks=0; ks<4; ++ks){
      h8 b0 = *(const h8*)(sm + ABUF + ks*8192 + rb0 + (16*g ^ sw0));
      h8 b1 = *(const h8*)(sm + ABUF + ks*8192 + rb1 + (16*g ^ sw1));
      #pragma unroll
      for (int t=0; t<8; ++t){
        acc[t][0] = MFMA16(aq2[ks][t], b0, acc[t][0]);
        acc[t][1] = MFMA16(aq2[ks][t], b1, acc[t][1]);
      }
    }
    // ---- x = relu(h2).w3 + b3 ----
    float xs0 = 0.f, xs1 = 0.f;
    #pragma unroll
    for (int t=0; t<8; ++t){
      f4 wv = *(const f4*)(qw3 + 16*t + 4*g);
      #pragma unroll
      for (int r=0; r<4; ++r){
        xs0 += fmaxf(acc[t][0][r],0.f)*wv[r];
        xs1 += fmaxf(acc[t][1][r],0.f)*wv[r];
      }
    }
    xs0 += __shfl_xor(xs0,16,64); xs0 += __shfl_xor(xs0,32,64);
    xs1 += __shfl_xor(xs1,16,64); xs1 += __shfl_xor(xs1,32,64);
    const float b3 = qb3[0];
    xs0 += b3; xs1 += b3;
    xsum0 += xs0; xsum1 += xs1;

    // ---- message net (writers: limbs 0..9) ----
    if (limb < 10){
      const float tx0 = tanh_fast(xs0), tx1 = tanh_fast(xs1);
      h8 tf0 = tanh8(bf1[0]), tf1 = tanh8(bf1[1]);
      // m1: init = mb1 + tx*wx (rank-1, wx = mw1 row 0); one MFMA block for mi
      #pragma unroll
      for (int t=0; t<8; ++t){
        f4 bm = *(const f4*)(mb1 + 16*t + 4*g);
        f4 wx = *(const f4*)(mw1 + 16*t + 4*g);
        acc[t][0] = bm + tx0*wx;
        acc[t][1] = bm + tx1*wx;
      }
      #pragma unroll
      for (int t=0; t<8; ++t){
        h8 a = *(const h8*)(sm + LM1 + (16*t+li)*64 + (16*g ^ swA));
        acc[t][0] = MFMA16(a, tf0, acc[t][0]);
        acc[t][1] = MFMA16(a, tf1, acc[t][1]);
      }
      #pragma unroll
      for (int t=0; t<8; ++t){
        const int c = (t&1)*32 + 8*g;
        *(h4*)(sm + ABUF + (t>>1)*8192 + rb0 + (c ^ sw0)) = relu4h(acc[t][0]);
        *(h4*)(sm + ABUF + (t>>1)*8192 + rb1 + (c ^ sw1)) = relu4h(acc[t][1]);
      }
      // m2: A-frags from LDS (swizzled), bias via VALU init
      #pragma unroll
      for (int t=0; t<8; ++t){
        f4 bv = *(const f4*)(mb2 + 16*t + 4*g);
        acc[t][0] = bv; acc[t][1] = bv;
      }
      #pragma unroll
      for (int ks=0; ks<4; ++ks){
        h8 b0 = *(const h8*)(sm + ABUF + ks*8192 + rb0 + (16*g ^ sw0));
        h8 b1 = *(const h8*)(sm + ABUF + ks*8192 + rb1 + (16*g ^ sw1));
        #pragma unroll
        for (int t=0; t<8; ++t){
          h8 a = *(const h8*)(sm + LM2 + ks*8192 + (16*t+li)*64 + (16*g ^ swA));
          acc[t][0] = MFMA16(a, b0, acc[t][0]);
          acc[t][1] = MFMA16(a, b1, acc[t][1]);
        }
      }
      #pragma unroll
      for (int t=0; t<8; ++t){
        const int c = (t&1)*32 + 8*g;
        *(h4*)(sm + ABUF + (t>>1)*8192 + rb0 + (c ^ sw0)) = relu4h(acc[t][0]);
        *(h4*)(sm + ABUF + (t>>1)*8192 + rb1 + (c ^ sw1)) = relu4h(acc[t][1]);
      }
      // m3: 64 feats, A-frags from global (L1/L2-hot), bias via VALU init
      f4 accN[4][2];
      #pragma unroll
      for (int t=0; t<4; ++t){
        f4 bv = *(const f4*)(mb3 + 16*t + 4*g);
        accN[t][0] = bv; accN[t][1] = bv;
      }
      #pragma unroll
      for (int ks=0; ks<4; ++ks){
        h8 b0 = *(const h8*)(sm + ABUF + ks*8192 + rb0 + (16*g ^ sw0));
        h8 b1 = *(const h8*)(sm + ABUF + ks*8192 + rb1 + (16*g ^ sw1));
        #pragma unroll
        for (int t=0; t<4; ++t){
          h8 a = *(const h8*)(ws + WM3E + ks*2048 + (16*t+li)*32 + 8*g);
          accN[t][0] = MFMA16(a, b0, accN[t][0]);
          accN[t][1] = MFMA16(a, b1, accN[t][1]);
        }
      }
      // l2 norm + store md to this depth's msg slot (swizzled)
      float s0=0.f, s1=0.f;
      #pragma unroll
      for (int t=0; t<4; ++t)
        #pragma unroll
        for (int r=0; r<4; ++r){
          s0 += accN[t][0][r]*accN[t][0][r];
          s1 += accN[t][1][r]*accN[t][1][r];
        }
      s0 += __shfl_xor(s0,16,64); s0 += __shfl_xor(s0,32,64);
      s1 += __shfl_xor(s1,16,64); s1 += __shfl_xor(s1,32,64);
      const float inv0 = 1.0f/fmaxf(sqrtf(s0),1e-12f);
      const float inv1 = 1.0f/fmaxf(sqrtf(s1),1e-12f);
      char* md = sm + MSG + depth*16384;
      #pragma unroll
      for (int t=0; t<4; ++t){
        const int c = (t&1)*32 + 8*g;
        f4 v0 = accN[t][0], v1 = accN[t][1];
        union { h4 v4; h2v p[2]; } u0, u1;
        u0.p[0] = cvt2(v0[0]*inv0, v0[1]*inv0);
        u0.p[1] = cvt2(v0[2]*inv0, v0[3]*inv0);
        u1.p[0] = cvt2(v1[0]*inv1, v1[1]*inv1);
        u1.p[1] = cvt2(v1[2]*inv1, v1[3]*inv1);
        *(h4*)(md + (t>>1)*8192 + rb0 + (c ^ sw0)) = u0.v4;
        *(h4*)(md + (t>>1)*8192 + rb1 + (c ^ sw1)) = u1.v4;
      }
    }
  }
  if (g == 0){
    out[rbase + li]      = xsum0;
    out[rbase + 16 + li] = xsum1;
  }
}

extern "C" void kernel_launch(void* const* d_in, const int* in_sizes, int n_in,
                              void* d_out, int out_size, void* d_ws, size_t ws_size,
                              hipStream_t stream) {
  (void)in_sizes; (void)n_in; (void)out_size; (void)ws_size;
  const float* state  = (const float*)d_in[0];
  const float* action = (const float*)d_in[1];
  const float* qw1 = (const float*)d_in[2];
  const float* qb1 = (const float*)d_in[3];
  const float* qw2 = (const float*)d_in[4];
  const float* qb2 = (const float*)d_in[5];
  const float* qw3 = (const float*)d_in[6];
  const float* qb3 = (const float*)d_in[7];
  const float* mw1 = (const float*)d_in[8];
  const float* mb1 = (const float*)d_in[9];
  const float* mw2 = (const float*)d_in[10];
  const float* mb2 = (const float*)d_in[11];
  const float* mw3 = (const float*)d_in[12];
  const float* mb3 = (const float*)d_in[13];
  _Float16* ws = (_Float16*)d_ws;
  float* out = (float*)d_out;

  (void)hipFuncSetAttribute((const void*)critic_all,
                            hipFuncAttributeMaxDynamicSharedMemorySize, LDS_TOTAL);

  critic_prep<<<208, 256, 0, stream>>>(qw1, qw2, mw1, mw2, mw3, ws);
  critic_all<<<256, 256, LDS_TOTAL, stream>>>(
      state, action, qw1, qb1, qb2, qw3, qb3, mw1, mb1, mb2, mb3, ws, out);
}

// Round 6
// 140.561 us; speedup vs baseline: 2.2704x; 1.1692x over previous
//
#include <hip/hip_runtime.h>

#define BATCHN 32768

typedef _Float16 h8  __attribute__((ext_vector_type(8)));
typedef _Float16 h4  __attribute__((ext_vector_type(4)));
typedef _Float16 h2v __attribute__((ext_vector_type(2)));
typedef __fp16   fp16x2 __attribute__((ext_vector_type(2)));
typedef float    f4  __attribute__((ext_vector_type(4)));
typedef unsigned int u32x4 __attribute__((ext_vector_type(4)));

// ---- ws layout (f16 elements) ----
// WQ1 [2][128][32] @0      linear (register A-frags)
// WQ2 [4][128][32] @8192   linear (register A-frags)
// WM1 [2][128][32] @24576  col-swizzled (to LDS; blk1: kk0=mw1 row0, kk1=mb1)
// WM2 [5][128][32] @32768  col-swizzled (to LDS; blk4: kk0=mb2)
// WM3 [5][64][32]  @53248  linear (global A-frags; blk4: kk0=mb3)
#define WM1E 24576
#define WM2E 32768
#define WM3E 53248

// ---- LDS layout (bytes); rows 64B (32 f16), col-XOR swizzled ----
#define LM1  0        // [2][128][32] f16 = 16384
#define LM2  16384    // [5][128][32] f16 = 40960
#define ABUF 57344    // 4 k-blocks x [128][32] f16 = 32768
#define MSG  90112    // 4 depths x 2 cidx x [128][32] f16 = 65536
#define LDS_TOTAL 155648

#define MFMA16(a,b,c) __builtin_amdgcn_mfma_f32_16x16x32_f16(a,b,c,0,0,0)

__device__ __forceinline__ float tanh_fast(float v){
  float e = __expf(2.0f*v);
  return 1.0f - 2.0f/(e+1.0f);
}
__device__ __forceinline__ h2v cvt2(float a, float b){
  fp16x2 t = __builtin_amdgcn_cvt_pkrtz(a, b);
  union { fp16x2 i; h2v o; } u; u.i = t; return u.o;
}
__device__ __forceinline__ h4 relu4h(f4 v){
  union { h4 v4; h2v p[2]; } u;
  u.p[0] = cvt2(fmaxf(v[0],0.f), fmaxf(v[1],0.f));
  u.p[1] = cvt2(fmaxf(v[2],0.f), fmaxf(v[3],0.f));
  return u.v4;
}
__device__ __forceinline__ h8 pack8(f4 a, f4 b){
  union { h8 v8; h2v p[4]; } u;
  u.p[0] = cvt2(a[0],a[1]); u.p[1] = cvt2(a[2],a[3]);
  u.p[2] = cvt2(b[0],b[1]); u.p[3] = cvt2(b[2],b[3]);
  return u.v8;
}
__device__ __forceinline__ h8 tanh8(h8 s){
  h8 r;
  #pragma unroll
  for (int j=0;j<8;++j) r[j] = (_Float16)tanh_fast((float)s[j]);
  return r;
}

// ---------------- weight prep: fp32 -> f16 blocked (+swizzled) layouts ----------------
__global__ void critic_prep(const float* __restrict__ qw1, const float* __restrict__ qw2,
                            const float* __restrict__ mw1, const float* __restrict__ mb1,
                            const float* __restrict__ mw2, const float* __restrict__ mb2,
                            const float* __restrict__ mw3, const float* __restrict__ mb3,
                            _Float16* __restrict__ ws)
{
  int i = blockIdx.x*blockDim.x + threadIdx.x;
  if (i < 8192){ int ks=i>>12, r=i&4095, f=r>>5, kk=r&31;
    ws[i] = (_Float16)(ks==0 ? qw1[kk*128+f] : qw1[(33+kk)*128+f]); return; }
  i -= 8192;
  if (i < 16384){ int ks=i>>12, r=i&4095, f=r>>5, kk=r&31;
    ws[8192+i] = (_Float16)qw2[(ks*32+kk)*128+f]; return; }
  i -= 16384;
  if (i < 8192){ int blk=i>>12, r=i&4095, f=r>>5, p=r&31;
    int kk = p ^ (((f>>1)&3)<<3);                     // col-swizzle
    float v = (blk==0) ? mw1[(1+kk)*128+f]
                       : (kk==0 ? mw1[f] : (kk==1 ? mb1[f] : 0.f));
    ws[WM1E+i] = (_Float16)v; return; }
  i -= 8192;
  if (i < 20480){ int ks=i>>12, r=i&4095, f=r>>5, p=r&31;
    int kk = p ^ (((f>>1)&3)<<3);                     // col-swizzle
    float v = (ks<4) ? mw2[(ks*32+kk)*128+f] : (kk==0 ? mb2[f] : 0.f);
    ws[WM2E+i] = (_Float16)v; return; }
  i -= 20480;
  if (i < 10240){ int ks=i>>11, r=i&2047, f=r>>5, kk=r&31;    // linear
    float v = (ks<4) ? mw3[(ks*32+kk)*64+f] : (kk==0 ? mb3[f] : 0.f);
    ws[WM3E+i] = (_Float16)v; return; }
}

// ---------------- single fused kernel: all 20 limbs, DFS, one barrier ----------------
__global__ __launch_bounds__(256,1) void critic_all(
    const float* __restrict__ state, const float* __restrict__ action,
    const float* __restrict__ qw1, const float* __restrict__ qb1,
    const float* __restrict__ qb2, const float* __restrict__ qw3,
    const float* __restrict__ qb3,
    const _Float16* __restrict__ ws, float* __restrict__ out)
{
  extern __shared__ char sm[];
  const int tid = threadIdx.x, lane = tid & 63;
  const int w = tid >> 6, g = lane >> 4, li = lane & 15;
  const int rbase = blockIdx.x*128 + w*32;

  // copy swizzled m1,m2 weights into LDS (57344 B from ws byte 49152)
  for (int off = tid*16; off < 57344; off += 4096)
    *(u32x4*)(sm + off) = *(const u32x4*)((const char*)ws + 49152 + off);

  // persistent q1/q2 A-fragments (192 VGPRs), loaded once from global
  h8 aq1[2][8], aq2[4][8];
  #pragma unroll
  for (int ks=0; ks<2; ++ks)
    #pragma unroll
    for (int t=0; t<8; ++t)
      aq1[ks][t] = *(const h8*)(ws + ks*4096 + (16*t+li)*32 + 8*g);
  #pragma unroll
  for (int ks=0; ks<4; ++ks)
    #pragma unroll
    for (int t=0; t<8; ++t)
      aq2[ks][t] = *(const h8*)(ws + 8192 + ks*4096 + (16*t+li)*32 + 8*g);

  __syncthreads();   // the only barrier

  // loop-invariant swizzle: all tile rows r have s(r) = (li>>1)&3
  const int swA = ((li>>1)&3)<<4;
  const int rb0 = (w*32 + li)*64, rb1 = (w*32 + 16 + li)*64;
  const int cB  = 16*g ^ swA;              // B-frag/A-frag read col (bytes)

  const h8 hzero = {};
  h8 conef = hzero; if (g==0) conef[0] = (_Float16)1.0f;   // {1,0,...} bias column
  const f4 z4 = {0.f,0.f,0.f,0.f};
  float xsum0 = 0.f, xsum1 = 0.f;

  const float* srow0 = state + (size_t)(rbase+li)*640 + 8*g;
  const float* srow1 = state + (size_t)(rbase+16+li)*640 + 8*g;

  // DFS order + depths (5/3 bits per entry)
  const unsigned long long SEQ0 =
    (0ull)|(1ull<<5)|(3ull<<10)|(7ull<<15)|(15ull<<20)|(16ull<<25)|(8ull<<30)|
    (17ull<<35)|(18ull<<40)|(4ull<<45)|(9ull<<50)|(19ull<<55);
  const unsigned long long SEQ1 =
    (10ull)|(2ull<<5)|(5ull<<10)|(11ull<<15)|(12ull<<20)|(6ull<<25)|(13ull<<30)|(14ull<<35);
  const unsigned long long DEPS =
    (0ull)|(1ull<<3)|(2ull<<6)|(3ull<<9)|(4ull<<12)|(4ull<<15)|(3ull<<18)|(4ull<<21)|
    (4ull<<24)|(2ull<<27)|(3ull<<30)|(4ull<<33)|(3ull<<36)|(1ull<<39)|(2ull<<42)|
    (3ull<<45)|(3ull<<48)|(2ull<<51)|(3ull<<54)|(3ull<<57);

  #pragma unroll 1
  for (int i = 0; i < 20; ++i){
    const int limb  = (int)(((i<12) ? (SEQ0>>(5*i)) : (SEQ1>>(5*(i-12)))) & 31);
    const int depth = (int)((DEPS >> (3*i)) & 7);
    const int cidx  = (limb-1) & 1;

    // ---- stage: state -> registers, act scalars ----
    f4 va0 = *(const f4*)(srow0 + limb*32), vb0 = *(const f4*)(srow0 + limb*32 + 4);
    f4 va1 = *(const f4*)(srow1 + limb*32), vb1 = *(const f4*)(srow1 + limb*32 + 4);
    h8 bf00 = pack8(va0, vb0), bf01 = pack8(va1, vb1);
    const float a0 = action[(size_t)limb*BATCHN + rbase + li];
    const float a1 = action[(size_t)limb*BATCHN + rbase + 16 + li];

    // mi fragments from parent msg slot (wave-private, swizzled)
    h8 bf1[2];
    if (limb > 0){
      const char* mr = sm + MSG + (depth-1)*16384 + cidx*8192;
      bf1[0] = *(const h8*)(mr + rb0 + cB);
      bf1[1] = *(const h8*)(mr + rb1 + cB);
    } else { bf1[0] = hzero; bf1[1] = hzero; }

    // ---- q1: acc = qb1 + act*wa (rank-1) + state@W + mi@W ----
    f4 acc[8][2];
    #pragma unroll
    for (int t=0; t<8; ++t){
      f4 bv = *(const f4*)(qb1 + 16*t + 4*g);
      f4 wa = *(const f4*)(qw1 + 4096 + 16*t + 4*g);   // row 32 = action weights
      acc[t][0] = bv + a0*wa;
      acc[t][1] = bv + a1*wa;
    }
    #pragma unroll
    for (int t=0; t<8; ++t){
      acc[t][0] = MFMA16(aq1[0][t], bf00, acc[t][0]);
      acc[t][1] = MFMA16(aq1[0][t], bf01, acc[t][1]);
      acc[t][0] = MFMA16(aq1[1][t], bf1[0], acc[t][0]);
      acc[t][1] = MFMA16(aq1[1][t], bf1[1], acc[t][1]);
    }
    // handoff h1 -> ABUF (relu, f16, swizzled)
    #pragma unroll
    for (int t=0; t<8; ++t){
      const int c = ((t&1)*32 + 8*g) ^ swA;
      *(h4*)(sm + ABUF + (t>>1)*8192 + rb0 + c) = relu4h(acc[t][0]);
      *(h4*)(sm + ABUF + (t>>1)*8192 + rb1 + c) = relu4h(acc[t][1]);
    }

    // ---- q2 ----
    #pragma unroll
    for (int t=0; t<8; ++t){
      f4 bv = *(const f4*)(qb2 + 16*t + 4*g);
      acc[t][0] = bv; acc[t][1] = bv;
    }
    #pragma unroll
    for (int ks=0; ks<4; ++ks){
      h8 b0 = *(const h8*)(sm + ABUF + ks*8192 + rb0 + cB);
      h8 b1 = *(const h8*)(sm + ABUF + ks*8192 + rb1 + cB);
      #pragma unroll
      for (int t=0; t<8; ++t){
        acc[t][0] = MFMA16(aq2[ks][t], b0, acc[t][0]);
        acc[t][1] = MFMA16(aq2[ks][t], b1, acc[t][1]);
      }
    }
    // ---- x = relu(h2).w3 + b3 ----
    float xs0 = 0.f, xs1 = 0.f;
    #pragma unroll
    for (int t=0; t<8; ++t){
      f4 wv = *(const f4*)(qw3 + 16*t + 4*g);
      #pragma unroll
      for (int r=0; r<4; ++r){
        xs0 += fmaxf(acc[t][0][r],0.f)*wv[r];
        xs1 += fmaxf(acc[t][1][r],0.f)*wv[r];
      }
    }
    xs0 += __shfl_xor(xs0,16,64); xs0 += __shfl_xor(xs0,32,64);
    xs1 += __shfl_xor(xs1,16,64); xs1 += __shfl_xor(xs1,32,64);
    const float b3 = qb3[0];
    xs0 += b3; xs1 += b3;
    xsum0 += xs0; xsum1 += xs1;

    // ---- message net (writers: limbs 0..9) ----
    if (limb < 10){
      const float tx0 = tanh_fast(xs0), tx1 = tanh_fast(xs1);
      h8 tf0 = tanh8(bf1[0]), tf1 = tanh8(bf1[1]);
      h8 bx0 = hzero, bx1 = hzero;
      if (g==0){ bx0[0]=(_Float16)tx0; bx0[1]=(_Float16)1.0f;
                 bx1[0]=(_Float16)tx1; bx1[1]=(_Float16)1.0f; }
      // m1: blk1 x {tx,1} gives mw1row0*tx + mb1; blk0 x tanh(mi)
      #pragma unroll
      for (int t=0; t<8; ++t){
        h8 a0 = *(const h8*)(sm + LM1 + (16*t+li)*64 + cB);
        h8 a1 = *(const h8*)(sm + LM1 + 8192 + (16*t+li)*64 + cB);
        acc[t][0] = MFMA16(a1, bx0, z4);
        acc[t][0] = MFMA16(a0, tf0, acc[t][0]);
        acc[t][1] = MFMA16(a1, bx1, z4);
        acc[t][1] = MFMA16(a0, tf1, acc[t][1]);
      }
      #pragma unroll
      for (int t=0; t<8; ++t){
        const int c = ((t&1)*32 + 8*g) ^ swA;
        *(h4*)(sm + ABUF + (t>>1)*8192 + rb0 + c) = relu4h(acc[t][0]);
        *(h4*)(sm + ABUF + (t>>1)*8192 + rb1 + c) = relu4h(acc[t][1]);
      }
      // m2: bias via conef on blk4, then 4 ks blocks (all LDS, swizzled)
      #pragma unroll
      for (int t=0; t<8; ++t){
        h8 ab = *(const h8*)(sm + LM2 + 4*8192 + (16*t+li)*64 + cB);
        acc[t][0] = MFMA16(ab, conef, z4);
        acc[t][1] = MFMA16(ab, conef, z4);
      }
      #pragma unroll
      for (int ks=0; ks<4; ++ks){
        h8 b0 = *(const h8*)(sm + ABUF + ks*8192 + rb0 + cB);
        h8 b1 = *(const h8*)(sm + ABUF + ks*8192 + rb1 + cB);
        #pragma unroll
        for (int t=0; t<8; ++t){
          h8 a = *(const h8*)(sm + LM2 + ks*8192 + (16*t+li)*64 + cB);
          acc[t][0] = MFMA16(a, b0, acc[t][0]);
          acc[t][1] = MFMA16(a, b1, acc[t][1]);
        }
      }
      #pragma unroll
      for (int t=0; t<8; ++t){
        const int c = ((t&1)*32 + 8*g) ^ swA;
        *(h4*)(sm + ABUF + (t>>1)*8192 + rb0 + c) = relu4h(acc[t][0]);
        *(h4*)(sm + ABUF + (t>>1)*8192 + rb1 + c) = relu4h(acc[t][1]);
      }
      // m3: 64 feats, A-frags from global (linear), bias via conef blk4
      f4 accN[4][2];
      #pragma unroll
      for (int t=0; t<4; ++t){
        h8 ab = *(const h8*)(ws + WM3E + 4*2048 + (16*t+li)*32 + 8*g);
        accN[t][0] = MFMA16(ab, conef, z4);
        accN[t][1] = MFMA16(ab, conef, z4);
      }
      #pragma unroll
      for (int ks=0; ks<4; ++ks){
        h8 b0 = *(const h8*)(sm + ABUF + ks*8192 + rb0 + cB);
        h8 b1 = *(const h8*)(sm + ABUF + ks*8192 + rb1 + cB);
        #pragma unroll
        for (int t=0; t<4; ++t){
          h8 a = *(const h8*)(ws + WM3E + ks*2048 + (16*t+li)*32 + 8*g);
          accN[t][0] = MFMA16(a, b0, accN[t][0]);
          accN[t][1] = MFMA16(a, b1, accN[t][1]);
        }
      }
      // l2 norm + store md to this depth's msg slot (swizzled)
      float s0=0.f, s1=0.f;
      #pragma unroll
      for (int t=0; t<4; ++t)
        #pragma unroll
        for (int r=0; r<4; ++r){
          s0 += accN[t][0][r]*accN[t][0][r];
          s1 += accN[t][1][r]*accN[t][1][r];
        }
      s0 += __shfl_xor(s0,16,64); s0 += __shfl_xor(s0,32,64);
      s1 += __shfl_xor(s1,16,64); s1 += __shfl_xor(s1,32,64);
      const float inv0 = 1.0f/fmaxf(sqrtf(s0),1e-12f);
      const float inv1 = 1.0f/fmaxf(sqrtf(s1),1e-12f);
      char* md = sm + MSG + depth*16384;
      #pragma unroll
      for (int t=0; t<4; ++t){
        const int c = ((t&1)*32 + 8*g) ^ swA;
        f4 v0 = accN[t][0], v1 = accN[t][1];
        union { h4 v4; h2v p[2]; } u0, u1;
        u0.p[0] = cvt2(v0[0]*inv0, v0[1]*inv0);
        u0.p[1] = cvt2(v0[2]*inv0, v0[3]*inv0);
        u1.p[0] = cvt2(v1[0]*inv1, v1[1]*inv1);
        u1.p[1] = cvt2(v1[2]*inv1, v1[3]*inv1);
        *(h4*)(md + (t>>1)*8192 + rb0 + c) = u0.v4;
        *(h4*)(md + (t>>1)*8192 + rb1 + c) = u1.v4;
      }
    }
  }
  if (g == 0){
    out[rbase + li]      = xsum0;
    out[rbase + 16 + li] = xsum1;
  }
}

extern "C" void kernel_launch(void* const* d_in, const int* in_sizes, int n_in,
                              void* d_out, int out_size, void* d_ws, size_t ws_size,
                              hipStream_t stream) {
  (void)in_sizes; (void)n_in; (void)out_size; (void)ws_size;
  const float* state  = (const float*)d_in[0];
  const float* action = (const float*)d_in[1];
  const float* qw1 = (const float*)d_in[2];
  const float* qb1 = (const float*)d_in[3];
  const float* qw2 = (const float*)d_in[4];
  const float* qb2 = (const float*)d_in[5];
  const float* qw3 = (const float*)d_in[6];
  const float* qb3 = (const float*)d_in[7];
  const float* mw1 = (const float*)d_in[8];
  const float* mb1 = (const float*)d_in[9];
  const float* mw2 = (const float*)d_in[10];
  const float* mb2 = (const float*)d_in[11];
  const float* mw3 = (const float*)d_in[12];
  const float* mb3 = (const float*)d_in[13];
  _Float16* ws = (_Float16*)d_ws;
  float* out = (float*)d_out;

  (void)hipFuncSetAttribute((const void*)critic_all,
                            hipFuncAttributeMaxDynamicSharedMemorySize, LDS_TOTAL);

  critic_prep<<<248, 256, 0, stream>>>(qw1, qw2, mw1, mb1, mw2, mb2, mw3, mb3, ws);
  critic_all<<<256, 256, LDS_TOTAL, stream>>>(
      state, action, qw1, qb1, qb2, qw3, qb3, ws, out);
}